// Round 2
// baseline (159.547 us; speedup 1.0000x reference)
//
#include <hip/hip_runtime.h>

#define BLOCK 1024
#define D 256
#define NW 16          // waves per block
#define ALPHA_CAP 4096 // max rows/segment supported (mean 512, std ~23)

__global__ __launch_bounds__(BLOCK, 2)
void dynpool_kernel(const float* __restrict__ x,     // (n, 256) f32
                    const int* __restrict__ batch,   // (n,) sorted int32
                    float* __restrict__ out,         // (B, 256) f32
                    int n)
{
    __shared__ float alpha_s[ALPHA_CAP];
    __shared__ float zpart[NW][D];
    __shared__ float mw_s[NW], sw_s[NW];
    __shared__ float fct[NW + 1];   // per-wave exp factors + [NW]=1/(s_tot+eps)
    __shared__ float red2[NW + 1];  // energy partials + [NW]=squash scale
    __shared__ float zs[D];
    __shared__ int bounds[2];

    const int tid  = threadIdx.x;
    const int s    = blockIdx.x;
    const int wv   = tid >> 6;     // wave 0..15
    const int lane = tid & 63;

    if (tid == 0) {
        int lo = 0, hi = n;
        while (lo < hi) { int mid = (lo + hi) >> 1; if (batch[mid] < s) lo = mid + 1; else hi = mid; }
        bounds[0] = lo;
        int lo2 = lo, hi2 = n;
        while (lo2 < hi2) { int mid = (lo2 + hi2) >> 1; if (batch[mid] < s + 1) lo2 = mid + 1; else hi2 = mid; }
        bounds[1] = lo2;
    }
    __syncthreads();
    const int start = bounds[0];
    const int cnt   = bounds[1] - bounds[0];

    if (cnt == 0) {                     // empty segment: segment_sum -> 0
        if (tid < D) out[(size_t)s * D + tid] = 0.f;
        return;
    }

    for (int r = tid; r < cnt; r += BLOCK) alpha_s[r] = 0.f;

    float zr[4] = {0.f, 0.f, 0.f, 0.f}; // z_squashed cols lane*4..+3 (0 => pass 0 is uniform softmax)
    __syncthreads();

    for (int iter = 0; iter < 4; ++iter) {
        // ---- fused pass: alpha_r += <x_r, z_sq>; online softmax-pool into (m,s,za) ----
        float m_run = -INFINITY, s_run = 0.f;
        float za[4] = {0.f, 0.f, 0.f, 0.f};
        for (int r = wv; r < cnt; r += NW) {
            const float4 v = *(const float4*)(x + ((size_t)(start + r)) * D + lane * 4);
            float dt = v.x * zr[0] + v.y * zr[1] + v.z * zr[2] + v.w * zr[3];
#pragma unroll
            for (int off = 32; off; off >>= 1) dt += __shfl_xor(dt, off);
            const float a_new = alpha_s[r] + dt;     // all lanes agree
            if (lane == 0) alpha_s[r] = a_new;       // persist for next pass
            const float mn = fmaxf(m_run, a_new);
            const float sc = __expf(m_run - mn);     // 0 on first row (m_run=-inf)
            const float w  = __expf(a_new - mn);
            s_run = s_run * sc + w;
            za[0] = za[0] * sc + w * v.x;
            za[1] = za[1] * sc + w * v.y;
            za[2] = za[2] * sc + w * v.z;
            za[3] = za[3] * sc + w * v.w;
            m_run = mn;
        }

        // ---- merge the 16 per-wave partials ----
        if (lane == 0) { mw_s[wv] = m_run; sw_s[wv] = s_run; }
#pragma unroll
        for (int j = 0; j < 4; ++j) zpart[wv][lane * 4 + j] = za[j];
        __syncthreads();

        if (tid == 0) {
            float mg = -INFINITY;
            for (int h = 0; h < NW; ++h) mg = fmaxf(mg, mw_s[h]);   // finite: cnt>0 => wave0 has a row
            float st = 0.f;
            for (int h = 0; h < NW; ++h) {
                const float f = __expf(mw_s[h] - mg);               // 0 for row-less waves
                fct[h] = f;
                st += sw_s[h] * f;
            }
            fct[NW] = 1.f / (st + 1e-16f);
        }
        __syncthreads();

        float zc = 0.f;
        if (tid < D) {
#pragma unroll
            for (int h = 0; h < NW; ++h) zc += zpart[h][tid] * fct[h];
            zc *= fct[NW];
        }

        if (iter == 3) {
            if (tid < D) out[(size_t)s * D + tid] = zc;
            break;
        }

        // ---- energy + squash ----
        float e = (tid < D) ? zc * zc : 0.f;
#pragma unroll
        for (int off = 32; off; off >>= 1) e += __shfl_xor(e, off);
        if (lane == 0) red2[wv] = e;
        __syncthreads();
        if (tid == 0) {
            float E = 0.f;
            for (int h = 0; h < NW; ++h) E += red2[h];
            red2[NW] = (E > 0.f) ? (sqrtf(E) / (1.f + E)) : 0.f;
        }
        __syncthreads();
        const float scale = red2[NW];
        if (tid < D) zs[tid] = zc * scale;
        __syncthreads();
#pragma unroll
        for (int j = 0; j < 4; ++j) zr[j] = zs[lane * 4 + j];
    }
}

extern "C" void kernel_launch(void* const* d_in, const int* in_sizes, int n_in,
                              void* d_out, int out_size, void* d_ws, size_t ws_size,
                              hipStream_t stream) {
    const float* x   = (const float*)d_in[0];
    const int* batch = (const int*)d_in[1];
    float* out       = (float*)d_out;
    const int n = in_sizes[1];          // 262144
    const int B = out_size / D;         // 512
    dynpool_kernel<<<B, BLOCK, 0, stream>>>(x, batch, out, n);
}